// Round 3
// baseline (653.142 us; speedup 1.0000x reference)
//
#include <hip/hip_runtime.h>
#include <hip/hip_bf16.h>
#include <math.h>

#define NUM_GRAPHS 1024

typedef __attribute__((ext_vector_type(8))) short bf16x8;
typedef __attribute__((ext_vector_type(4))) float f32x4;

static __device__ __forceinline__ unsigned short f2bf(float f) {
    union { float f; unsigned u; } v; v.f = f;
    unsigned r = v.u + 0x7fffu + ((v.u >> 16) & 1u);   // round-to-nearest-even
    return (unsigned short)(r >> 16);
}
static __device__ __forceinline__ float bf_lo(unsigned u) { return __uint_as_float(u << 16); }
static __device__ __forceinline__ float bf_hi(unsigned u) { return __uint_as_float(u & 0xffff0000u); }

// ---------------- combined pre-pass: deg histogram + per-edge rank, and x->bf16 ----------------
__global__ void k_pre(const int* __restrict__ eiDst, int E,
                      int* __restrict__ deg, int* __restrict__ rank,
                      const float* __restrict__ x, int n4, unsigned* __restrict__ xb,
                      int eb) {
    if ((int)blockIdx.x < eb) {
        int e = blockIdx.x * 256 + threadIdx.x;
        if (e < E) rank[e] = atomicAdd(&deg[eiDst[e]], 1);
    } else {
        int i = (blockIdx.x - eb) * 256 + threadIdx.x;
        int stride = (gridDim.x - eb) * 256;
        const float4* x4 = (const float4*)x;
        for (; i < n4; i += stride) {
            float4 v = x4[i];
            unsigned lo = (unsigned)f2bf(v.x) | ((unsigned)f2bf(v.y) << 16);
            unsigned hi = (unsigned)f2bf(v.z) | ((unsigned)f2bf(v.w) << 16);
            ((uint2*)xb)[i] = make_uint2(lo, hi);
        }
    }
}

// ---------------- scans ----------------
__global__ void k_scan1(const int* __restrict__ deg, int N,
                        int* __restrict__ excl, int* __restrict__ bsum) {
    __shared__ int s[256];
    int i = blockIdx.x * 256 + threadIdx.x;
    int v = (i < N) ? deg[i] : 0;
    s[threadIdx.x] = v;
    __syncthreads();
    for (int off = 1; off < 256; off <<= 1) {
        int t = (threadIdx.x >= off) ? s[threadIdx.x - off] : 0;
        __syncthreads();
        s[threadIdx.x] += t;
        __syncthreads();
    }
    if (i < N) excl[i] = s[threadIdx.x] - v;
    if (threadIdx.x == 255) bsum[blockIdx.x] = s[255];
}

__global__ void k_scan2(int* __restrict__ bsum, int nb) {
    __shared__ int s[1024];
    int t = threadIdx.x;
    int v = (t < nb) ? bsum[t] : 0;
    s[t] = v;
    __syncthreads();
    for (int off = 1; off < 1024; off <<= 1) {
        int u = (t >= off) ? s[t - off] : 0;
        __syncthreads();
        s[t] += u;
        __syncthreads();
    }
    if (t < nb) bsum[t] = s[t] - v;   // exclusive block offsets
}

__global__ void k_scan3(const int* __restrict__ excl, const int* __restrict__ bsum,
                        int N, int E, int* __restrict__ rp) {
    int i = blockIdx.x * 256 + threadIdx.x;
    if (i < N) rp[i] = excl[i] + bsum[i >> 8];
    if (i == 0) rp[N] = E;
}

// Atomic-free fill, 3 temporal passes over dst ranges (L2-resident write window).
#define FILL_PASSES 3
#define FILL_RANGE 33334
__global__ void k_fill3(const int* __restrict__ ei, const int* __restrict__ rank,
                        int E, const int* __restrict__ rp, int* __restrict__ srcs) {
    const int tid0 = blockIdx.x * 256 + threadIdx.x;
    const int stride = gridDim.x * 256;
    for (int pass = 0; pass < FILL_PASSES; ++pass) {
        const int lo = pass * FILL_RANGE;
        const int hi = lo + FILL_RANGE;
        for (int e = tid0; e < E; e += stride) {
            int d = ei[(size_t)E + e];
            if (d >= lo && d < hi) {
                srcs[rp[d] + rank[e]] = ei[e];
            }
        }
    }
}

// ---------------- weight prep: 4x fp32 W[k][n] -> bf16 W^T[n][k] in one dispatch ----------------
__global__ void k_prepw4(const float* __restrict__ W0, const float* __restrict__ W1,
                         const float* __restrict__ W2, const float* __restrict__ W3,
                         unsigned short* __restrict__ wt) {
    int b = blockIdx.x >> 6;   // 0..3
    const float* W = (b == 0) ? W0 : (b == 1) ? W1 : (b == 2) ? W2 : W3;
    int idx = (blockIdx.x & 63) * 256 + threadIdx.x;   // 0..16383
    int k = idx >> 7, n = idx & 127;
    wt[b * 16384 + n * 128 + k] = f2bf(W[idx]);
}

// ---------------- fused GIN conv: gather-agg + 2-layer MLP ----------------
// XOR-chunk swizzle: (row, chunk of 8 elems) -> element row*128 + ((chunk ^ (row&7))*8)
__device__ __forceinline__ int swz_base(int row, int chunk) {
    return row * 128 + ((chunk ^ (row & 7)) << 3);
}

__global__ __launch_bounds__(256, 2)
void k_gin(const unsigned* __restrict__ H, const int* __restrict__ rp,
           const int* __restrict__ srcs, int N,
           const unsigned short* __restrict__ WaT, const float* __restrict__ ba,
           const unsigned short* __restrict__ WbT, const float* __restrict__ bb,
           unsigned short* __restrict__ Y) {
    __shared__ unsigned short lA[128 * 128];   // 32 KB: agg tile (bf16), then T tile
    __shared__ unsigned short lW[128 * 128];   // 32 KB: Wa^T, then Wb^T

    const int tid = threadIdx.x;
    const int lane = tid & 63;
    const int w = tid >> 6;              // wave 0..3
    const int wr = (w >> 1) * 64;        // wave row offset (matmul)
    const int wc = (w & 1) * 64;         // wave col offset (matmul)
    const int r0 = blockIdx.x * 128;

    // ---- stage Wa^T into lW (no barrier needed before gather: disjoint LDS) ----
    {
        const uint4* Wsrc = (const uint4*)WaT;
        #pragma unroll
        for (int i = 0; i < 8; ++i) {
            int c = tid + 256 * i;
            int row = c >> 4, q = c & 15;
            *(uint4*)&lW[swz_base(row, q)] = Wsrc[c];
        }
    }

    // ---- gather-aggregate 32 rows per wave (2-row software pipeline) ----
    // lane holds features 2*lane (lo) and 2*lane+1 (hi) of each row.
    for (int rr = 0; rr < 32; rr += 2) {
        const int rowA = w * 32 + rr;
        const int rowB = rowA + 1;
        const int gA = r0 + rowA;
        const int gB = r0 + rowB;
        float aL = 0.f, aH = 0.f, bL = 0.f, bH = 0.f;
        int jA = 0, eA = 0, jB = 0, eB = 0;
        if (gA < N) {
            unsigned s = H[(size_t)gA * 64 + lane];
            aL = bf_lo(s); aH = bf_hi(s);
            jA = rp[gA]; eA = rp[gA + 1];
        }
        if (gB < N) {
            unsigned s = H[(size_t)gB * 64 + lane];
            bL = bf_lo(s); bH = bf_hi(s);
            jB = rp[gB]; eB = rp[gB + 1];
        }
        // paired main loop: 8 row-loads in flight
        while (jA + 4 <= eA && jB + 4 <= eB) {
            int a0 = srcs[jA], a1 = srcs[jA + 1], a2 = srcs[jA + 2], a3 = srcs[jA + 3];
            int b0 = srcs[jB], b1 = srcs[jB + 1], b2 = srcs[jB + 2], b3 = srcs[jB + 3];
            unsigned va0 = H[(size_t)a0 * 64 + lane];
            unsigned va1 = H[(size_t)a1 * 64 + lane];
            unsigned va2 = H[(size_t)a2 * 64 + lane];
            unsigned va3 = H[(size_t)a3 * 64 + lane];
            unsigned vb0 = H[(size_t)b0 * 64 + lane];
            unsigned vb1 = H[(size_t)b1 * 64 + lane];
            unsigned vb2 = H[(size_t)b2 * 64 + lane];
            unsigned vb3 = H[(size_t)b3 * 64 + lane];
            aL += bf_lo(va0) + bf_lo(va1) + bf_lo(va2) + bf_lo(va3);
            aH += bf_hi(va0) + bf_hi(va1) + bf_hi(va2) + bf_hi(va3);
            bL += bf_lo(vb0) + bf_lo(vb1) + bf_lo(vb2) + bf_lo(vb3);
            bH += bf_hi(vb0) + bf_hi(vb1) + bf_hi(vb2) + bf_hi(vb3);
            jA += 4; jB += 4;
        }
        for (; jA + 4 <= eA; jA += 4) {
            int a0 = srcs[jA], a1 = srcs[jA + 1], a2 = srcs[jA + 2], a3 = srcs[jA + 3];
            unsigned v0 = H[(size_t)a0 * 64 + lane];
            unsigned v1 = H[(size_t)a1 * 64 + lane];
            unsigned v2 = H[(size_t)a2 * 64 + lane];
            unsigned v3 = H[(size_t)a3 * 64 + lane];
            aL += bf_lo(v0) + bf_lo(v1) + bf_lo(v2) + bf_lo(v3);
            aH += bf_hi(v0) + bf_hi(v1) + bf_hi(v2) + bf_hi(v3);
        }
        for (; jA < eA; ++jA) {
            unsigned v = H[(size_t)srcs[jA] * 64 + lane];
            aL += bf_lo(v); aH += bf_hi(v);
        }
        for (; jB + 4 <= eB; jB += 4) {
            int b0 = srcs[jB], b1 = srcs[jB + 1], b2 = srcs[jB + 2], b3 = srcs[jB + 3];
            unsigned v0 = H[(size_t)b0 * 64 + lane];
            unsigned v1 = H[(size_t)b1 * 64 + lane];
            unsigned v2 = H[(size_t)b2 * 64 + lane];
            unsigned v3 = H[(size_t)b3 * 64 + lane];
            bL += bf_lo(v0) + bf_lo(v1) + bf_lo(v2) + bf_lo(v3);
            bH += bf_hi(v0) + bf_hi(v1) + bf_hi(v2) + bf_hi(v3);
        }
        for (; jB < eB; ++jB) {
            unsigned v = H[(size_t)srcs[jB] * 64 + lane];
            bL += bf_lo(v); bH += bf_hi(v);
        }
        // store to lA: lane's element index = 2*lane -> chunk lane>>2, offset (lane&3)*2
        unsigned pA = (unsigned)f2bf(aL) | ((unsigned)f2bf(aH) << 16);
        unsigned pB = (unsigned)f2bf(bL) | ((unsigned)f2bf(bH) << 16);
        *(unsigned*)&lA[swz_base(rowA, lane >> 2) + ((lane & 3) << 1)] = pA;
        *(unsigned*)&lA[swz_base(rowB, lane >> 2) + ((lane & 3) << 1)] = pB;
    }
    __syncthreads();

    const int am = lane & 15;
    const int kq = (lane >> 4) * 8;             // quad k offset

    f32x4 acc[4][4];
    #pragma unroll
    for (int i = 0; i < 4; ++i)
        #pragma unroll
        for (int j = 0; j < 4; ++j) acc[i][j] = (f32x4){0.f, 0.f, 0.f, 0.f};

    // ---- matmul 1: T = A @ Wa ----
    #pragma unroll
    for (int ks = 0; ks < 4; ++ks) {
        int k0 = ks * 32 + kq;
        bf16x8 af[4], bq[4];
        #pragma unroll
        for (int i = 0; i < 4; ++i)
            af[i] = *(const bf16x8*)&lA[swz_base(wr + i * 16 + am, k0 >> 3)];
        #pragma unroll
        for (int j = 0; j < 4; ++j)
            bq[j] = *(const bf16x8*)&lW[swz_base(wc + j * 16 + am, k0 >> 3)];
        #pragma unroll
        for (int i = 0; i < 4; ++i)
            #pragma unroll
            for (int j = 0; j < 4; ++j)
                acc[i][j] = __builtin_amdgcn_mfma_f32_16x16x32_bf16(af[i], bq[j], acc[i][j], 0, 0, 0);
    }
    __syncthreads();   // all lA/lW reads complete

    // ---- T = relu(acc + ba) -> lA (bf16); restage lW = Wb^T ----
    #pragma unroll
    for (int j = 0; j < 4; ++j) {
        int col = wc + j * 16 + am;
        float bias = ba[col];
        #pragma unroll
        for (int i = 0; i < 4; ++i) {
            int rowb = wr + i * 16 + (lane >> 4) * 4;
            #pragma unroll
            for (int r = 0; r < 4; ++r) {
                float t = acc[i][j][r] + bias;
                t = t > 0.f ? t : 0.f;
                int row = rowb + r;
                lA[swz_base(row, col >> 3) + (col & 7)] = f2bf(t);
            }
        }
    }
    {
        const uint4* Wsrc = (const uint4*)WbT;
        #pragma unroll
        for (int i = 0; i < 8; ++i) {
            int c = tid + 256 * i;
            int row = c >> 4, q = c & 15;
            *(uint4*)&lW[swz_base(row, q)] = Wsrc[c];
        }
    }
    __syncthreads();

    // ---- matmul 2: R = T @ Wb ----
    #pragma unroll
    for (int i = 0; i < 4; ++i)
        #pragma unroll
        for (int j = 0; j < 4; ++j) acc[i][j] = (f32x4){0.f, 0.f, 0.f, 0.f};

    #pragma unroll
    for (int ks = 0; ks < 4; ++ks) {
        int k0 = ks * 32 + kq;
        bf16x8 af[4], bq[4];
        #pragma unroll
        for (int i = 0; i < 4; ++i)
            af[i] = *(const bf16x8*)&lA[swz_base(wr + i * 16 + am, k0 >> 3)];
        #pragma unroll
        for (int j = 0; j < 4; ++j)
            bq[j] = *(const bf16x8*)&lW[swz_base(wc + j * 16 + am, k0 >> 3)];
        #pragma unroll
        for (int i = 0; i < 4; ++i)
            #pragma unroll
            for (int j = 0; j < 4; ++j)
                acc[i][j] = __builtin_amdgcn_mfma_f32_16x16x32_bf16(af[i], bq[j], acc[i][j], 0, 0, 0);
    }

    // ---- epilogue: Y = relu(acc + bb), bf16 ----
    #pragma unroll
    for (int j = 0; j < 4; ++j) {
        int col = wc + j * 16 + am;
        float bias = bb[col];
        #pragma unroll
        for (int i = 0; i < 4; ++i) {
            int rowb = wr + i * 16 + (lane >> 4) * 4;
            #pragma unroll
            for (int r = 0; r < 4; ++r) {
                int row = r0 + rowb + r;
                if (row < N) {
                    float t = acc[i][j][r] + bias;
                    t = t > 0.f ? t : 0.f;
                    Y[(size_t)row * 128 + col] = f2bf(t);
                }
            }
        }
    }
}

// ---------------- pooling: g[batch[n]] += h[n] (bf16 in, fp32 atomic out) ----------------
#define PSTRIP 8
__global__ void k_pool(const unsigned* __restrict__ H, const int* __restrict__ batch,
                       int N, float* __restrict__ G) {
    int wid = (blockIdx.x * blockDim.x + threadIdx.x) >> 6;
    int lane = threadIdx.x & 63;
    int n0 = wid * PSTRIP;
    if (n0 >= N) return;
    int n1 = n0 + PSTRIP; if (n1 > N) n1 = N;
    const size_t fo = (size_t)lane * 2;
    int cur = batch[n0];
    float aL = 0.f, aH = 0.f;
    for (int n = n0; n < n1; ++n) {
        int b = batch[n];
        if (b != cur) {
            atomicAdd(&G[(size_t)cur * 128 + fo], aL);
            atomicAdd(&G[(size_t)cur * 128 + fo + 1], aH);
            aL = 0.f; aH = 0.f;
            cur = b;
        }
        unsigned v = H[(size_t)n * 64 + lane];
        aL += bf_lo(v);
        aH += bf_hi(v);
    }
    atomicAdd(&G[(size_t)cur * 128 + fo], aL);
    atomicAdd(&G[(size_t)cur * 128 + fo + 1], aH);
}

// ---------------- head: out = log_softmax(relu(g@Wl1+bl1)@Wl2+bl2) ----------------
__global__ void k_head(const float* __restrict__ G,
                       const float* __restrict__ Wl1, const float* __restrict__ bl1,
                       const float* __restrict__ Wl2, const float* __restrict__ bl2,
                       int C, float* __restrict__ out) {
    __shared__ float sg[128];
    __shared__ float sh[128];
    __shared__ float sl[16];
    int row = blockIdx.x;
    int t = threadIdx.x;
    sg[t] = G[(size_t)row * 128 + t];
    __syncthreads();
    float a = bl1[t];
    for (int k = 0; k < 128; ++k) a += sg[k] * Wl1[k * 128 + t];
    sh[t] = a > 0.f ? a : 0.f;
    __syncthreads();
    if (t < C) {
        float l = bl2[t];
        for (int k = 0; k < 128; ++k) l += sh[k] * Wl2[k * C + t];
        sl[t] = l;
    }
    __syncthreads();
    if (t < C) {
        float m = -1e30f;
        for (int j = 0; j < C; ++j) m = fmaxf(m, sl[j]);
        float s = 0.f;
        for (int j = 0; j < C; ++j) s += __expf(sl[j] - m);
        out[(size_t)row * C + t] = sl[t] - m - __logf(s);
    }
}

extern "C" void kernel_launch(void* const* d_in, const int* in_sizes, int n_in,
                              void* d_out, int out_size, void* d_ws, size_t ws_size,
                              hipStream_t stream) {
    const float* x    = (const float*)d_in[0];
    const int*   ei   = (const int*)d_in[1];     // [2][E]
    const int*   batch= (const int*)d_in[2];
    const float* W1a  = (const float*)d_in[3];
    const float* b1a  = (const float*)d_in[4];
    const float* W1b  = (const float*)d_in[5];
    const float* b1b  = (const float*)d_in[6];
    const float* W2a  = (const float*)d_in[7];
    const float* b2a  = (const float*)d_in[8];
    const float* W2b  = (const float*)d_in[9];
    const float* b2b  = (const float*)d_in[10];
    const float* Wl1  = (const float*)d_in[11];
    const float* bl1  = (const float*)d_in[12];
    const float* Wl2  = (const float*)d_in[13];
    const float* bl2  = (const float*)d_in[14];
    float* out = (float*)d_out;

    const int N = in_sizes[2];
    const int E = in_sizes[1] / 2;
    const int C = in_sizes[13] / 128;

    char* p = (char*)d_ws;
    auto alloc = [&](size_t bytes) {
        char* r = p;
        p += (bytes + 255) & ~(size_t)255;
        return r;
    };
    unsigned* xb = (unsigned*)alloc((size_t)N * 64 * 4);          // x in bf16
    unsigned* hA = (unsigned*)alloc((size_t)N * 64 * 4);          // conv1 output (bf16)
    unsigned* hB = (unsigned*)alloc((size_t)N * 64 * 4);          // conv2 output (bf16)
    float* g   = (float*)alloc((size_t)NUM_GRAPHS * 128 * 4);
    int* deg   = (int*)alloc((size_t)N * 4);
    int* excl  = (int*)alloc((size_t)N * 4);
    int* rp    = (int*)alloc((size_t)(N + 1) * 4);
    int* rank  = (int*)alloc((size_t)E * 4);
    int* bsum  = (int*)alloc(4096);
    int* srcs  = (int*)alloc((size_t)E * 4);
    unsigned short* wt = (unsigned short*)alloc((size_t)4 * 16384 * 2);
    (void)ws_size; (void)n_in; (void)out_size;

    const int nb = (N + 255) / 256;
    const int eb = (E + 255) / 256;

    hipMemsetAsync(deg, 0, (size_t)N * 4, stream);
    hipMemsetAsync(g, 0, (size_t)NUM_GRAPHS * 128 * 4, stream);

    // pre-pass: deg+rank histogram and x->bf16 in one dispatch
    k_pre<<<eb + 4096, 256, 0, stream>>>(ei + E, E, deg, rank, x, N * 32, xb, eb);
    // scans -> row pointers
    k_scan1<<<nb, 256, 0, stream>>>(deg, N, excl, bsum);
    k_scan2<<<1, 1024, 0, stream>>>(bsum, nb);
    k_scan3<<<nb, 256, 0, stream>>>(excl, bsum, N, E, rp);
    k_fill3<<<2048, 256, 0, stream>>>(ei, rank, E, rp, srcs);
    // bf16 weights (all four in one dispatch)
    k_prepw4<<<256, 256, 0, stream>>>(W1a, W1b, W2a, W2b, wt);

    const int mb = (N + 127) / 128;

    // fused conv1 / conv2
    k_gin<<<mb, 256, 0, stream>>>(xb, rp, srcs, N, wt, b1a, wt + 16384, b1b,
                                  (unsigned short*)hA);
    k_gin<<<mb, 256, 0, stream>>>(hA, rp, srcs, N, wt + 2 * 16384, b2a, wt + 3 * 16384, b2b,
                                  (unsigned short*)hB);

    // pool + head
    const int pw = (N + PSTRIP - 1) / PSTRIP;
    const int pb = (pw + 3) / 4;
    k_pool<<<pb, 256, 0, stream>>>(hB, batch, N, g);
    k_head<<<NUM_GRAPHS, 128, 0, stream>>>(g, Wl1, bl1, Wl2, bl2, C, out);
}

// Round 4
// 439.139 us; speedup vs baseline: 1.4873x; 1.4873x over previous
//
#include <hip/hip_runtime.h>
#include <hip/hip_bf16.h>
#include <math.h>

#define NUM_GRAPHS 1024

typedef __attribute__((ext_vector_type(8))) short bf16x8;
typedef __attribute__((ext_vector_type(4))) float f32x4;

static __device__ __forceinline__ unsigned short f2bf(float f) {
    union { float f; unsigned u; } v; v.f = f;
    unsigned r = v.u + 0x7fffu + ((v.u >> 16) & 1u);   // round-to-nearest-even
    return (unsigned short)(r >> 16);
}
static __device__ __forceinline__ float bf_lo(unsigned u) { return __uint_as_float(u << 16); }
static __device__ __forceinline__ float bf_hi(unsigned u) { return __uint_as_float(u & 0xffff0000u); }

// ---------------- combined pre-pass: deg histogram + per-edge rank, and x->bf16 ----------------
__global__ void k_pre(const int* __restrict__ eiDst, int E,
                      int* __restrict__ deg, int* __restrict__ rank,
                      const float* __restrict__ x, int n4, unsigned* __restrict__ xb,
                      int eb) {
    if ((int)blockIdx.x < eb) {
        int e = blockIdx.x * 256 + threadIdx.x;
        if (e < E) rank[e] = atomicAdd(&deg[eiDst[e]], 1);
    } else {
        int i = (blockIdx.x - eb) * 256 + threadIdx.x;
        int stride = (gridDim.x - eb) * 256;
        const float4* x4 = (const float4*)x;
        for (; i < n4; i += stride) {
            float4 v = x4[i];
            unsigned lo = (unsigned)f2bf(v.x) | ((unsigned)f2bf(v.y) << 16);
            unsigned hi = (unsigned)f2bf(v.z) | ((unsigned)f2bf(v.w) << 16);
            ((uint2*)xb)[i] = make_uint2(lo, hi);
        }
    }
}

// ---------------- scans ----------------
__global__ void k_scan1(const int* __restrict__ deg, int N,
                        int* __restrict__ excl, int* __restrict__ bsum) {
    __shared__ int s[256];
    int i = blockIdx.x * 256 + threadIdx.x;
    int v = (i < N) ? deg[i] : 0;
    s[threadIdx.x] = v;
    __syncthreads();
    for (int off = 1; off < 256; off <<= 1) {
        int t = (threadIdx.x >= off) ? s[threadIdx.x - off] : 0;
        __syncthreads();
        s[threadIdx.x] += t;
        __syncthreads();
    }
    if (i < N) excl[i] = s[threadIdx.x] - v;
    if (threadIdx.x == 255) bsum[blockIdx.x] = s[255];
}

__global__ void k_scan2(int* __restrict__ bsum, int nb) {
    __shared__ int s[1024];
    int t = threadIdx.x;
    int v = (t < nb) ? bsum[t] : 0;
    s[t] = v;
    __syncthreads();
    for (int off = 1; off < 1024; off <<= 1) {
        int u = (t >= off) ? s[t - off] : 0;
        __syncthreads();
        s[t] += u;
        __syncthreads();
    }
    if (t < nb) bsum[t] = s[t] - v;   // exclusive block offsets
}

__global__ void k_scan3(const int* __restrict__ excl, const int* __restrict__ bsum,
                        int N, int E, int* __restrict__ rp) {
    int i = blockIdx.x * 256 + threadIdx.x;
    if (i < N) rp[i] = excl[i] + bsum[i >> 8];
    if (i == 0) rp[N] = E;
}

// Atomic-free fill, 3 temporal passes over dst ranges (L2-resident write window).
#define FILL_PASSES 3
#define FILL_RANGE 33334
__global__ void k_fill3(const int* __restrict__ ei, const int* __restrict__ rank,
                        int E, const int* __restrict__ rp, int* __restrict__ srcs) {
    const int tid0 = blockIdx.x * 256 + threadIdx.x;
    const int stride = gridDim.x * 256;
    for (int pass = 0; pass < FILL_PASSES; ++pass) {
        const int lo = pass * FILL_RANGE;
        const int hi = lo + FILL_RANGE;
        for (int e = tid0; e < E; e += stride) {
            int d = ei[(size_t)E + e];
            if (d >= lo && d < hi) {
                srcs[rp[d] + rank[e]] = ei[e];
            }
        }
    }
}

// ---------------- weight prep: 4x fp32 W[k][n] -> bf16 W^T[n][k] in one dispatch ----------------
__global__ void k_prepw4(const float* __restrict__ W0, const float* __restrict__ W1,
                         const float* __restrict__ W2, const float* __restrict__ W3,
                         unsigned short* __restrict__ wt) {
    int b = blockIdx.x >> 6;   // 0..3
    const float* W = (b == 0) ? W0 : (b == 1) ? W1 : (b == 2) ? W2 : W3;
    int idx = (blockIdx.x & 63) * 256 + threadIdx.x;   // 0..16383
    int k = idx >> 7, n = idx & 127;
    wt[b * 16384 + n * 128 + k] = f2bf(W[idx]);
}

// ---------------- quarter-wave aggregation (bf16 in/out, fp32 accumulate) ----------------
// 16 lanes per node, lane holds uint4 = 8 bf16 features. One load instruction
// moves up to 4 rows (1 KB) for 4 different dst nodes -> 4x fewer VMEM
// instructions than the wave-per-node variant at identical cache-line traffic.
__device__ __forceinline__ void acc8(float* a, uint4 v) {
    a[0] += bf_lo(v.x); a[1] += bf_hi(v.x);
    a[2] += bf_lo(v.y); a[3] += bf_hi(v.y);
    a[4] += bf_lo(v.z); a[5] += bf_hi(v.z);
    a[6] += bf_lo(v.w); a[7] += bf_hi(v.w);
}

__global__ __launch_bounds__(256, 8)
void k_aggq(const uint4* __restrict__ H4, const int* __restrict__ rp,
            const int* __restrict__ srcs, int N, uint4* __restrict__ out) {
    int gw = (blockIdx.x * blockDim.x + threadIdx.x) >> 6;   // wave id
    int lane = threadIdx.x & 63;
    int q = lane >> 4, ql = lane & 15;                       // quarter, lane-in-quarter
    int n = gw * 4 + q;
    if (gw * 4 >= N) return;
    bool act = (n < N);
    int nc = act ? n : 0;
    uint4 s0 = H4[(size_t)nc * 16 + ql];
    float a[8];
    a[0] = bf_lo(s0.x); a[1] = bf_hi(s0.x);
    a[2] = bf_lo(s0.y); a[3] = bf_hi(s0.y);
    a[4] = bf_lo(s0.z); a[5] = bf_hi(s0.z);
    a[6] = bf_lo(s0.w); a[7] = bf_hi(s0.w);
    int j = act ? rp[nc] : 0;
    int e = act ? rp[nc + 1] : 0;
    // 4-deep pipeline; per-lane (per-quarter) loop bounds, exec-masked divergence
    while (j + 4 <= e) {
        int i0 = srcs[j], i1 = srcs[j + 1], i2 = srcs[j + 2], i3 = srcs[j + 3];
        uint4 v0 = H4[(size_t)i0 * 16 + ql];
        uint4 v1 = H4[(size_t)i1 * 16 + ql];
        uint4 v2 = H4[(size_t)i2 * 16 + ql];
        uint4 v3 = H4[(size_t)i3 * 16 + ql];
        acc8(a, v0); acc8(a, v1); acc8(a, v2); acc8(a, v3);
        j += 4;
    }
    while (j < e) {
        uint4 v = H4[(size_t)srcs[j] * 16 + ql];
        acc8(a, v);
        ++j;
    }
    if (act) {
        uint4 o;
        o.x = (unsigned)f2bf(a[0]) | ((unsigned)f2bf(a[1]) << 16);
        o.y = (unsigned)f2bf(a[2]) | ((unsigned)f2bf(a[3]) << 16);
        o.z = (unsigned)f2bf(a[4]) | ((unsigned)f2bf(a[5]) << 16);
        o.w = (unsigned)f2bf(a[6]) | ((unsigned)f2bf(a[7]) << 16);
        out[(size_t)n * 16 + ql] = o;
    }
}

// ---------------- fused 2-layer MLP (bf16 in/out): Y = relu(relu(U@Wa+ba)@Wb+bb) ----------------
// XOR-chunk swizzle: (row, chunk of 8 elems) -> element row*128 + ((chunk ^ (row&7))*8)
__device__ __forceinline__ int swz_base(int row, int chunk) {
    return row * 128 + ((chunk ^ (row & 7)) << 3);
}

__global__ __launch_bounds__(256, 2)
void k_mlp(const unsigned short* __restrict__ U, int N,
           const unsigned short* __restrict__ WaT, const float* __restrict__ ba,
           const unsigned short* __restrict__ WbT, const float* __restrict__ bb,
           unsigned short* __restrict__ Y) {
    __shared__ unsigned short lA[128 * 128];   // 32 KB: A tile, then T tile
    __shared__ unsigned short lW[128 * 128];   // 32 KB: Wa^T, then Wb^T

    const int tid = threadIdx.x;
    const int lane = tid & 63;
    const int w = tid >> 6;              // wave 0..3
    const int wr = (w >> 1) * 64;        // wave row offset
    const int wc = (w & 1) * 64;         // wave col offset
    const int r0 = blockIdx.x * 128;

    // ---- stage A: bf16 global -> LDS (swizzled), 16B = one 8-elem chunk ----
    {
        const uint4* U4 = (const uint4*)U;
        #pragma unroll
        for (int i = 0; i < 8; ++i) {
            int c = tid + 256 * i;              // 0..2047
            int row = c >> 4, q = c & 15;
            uint4 v = (r0 + row < N) ? U4[(size_t)(r0 + row) * 16 + q]
                                     : make_uint4(0u, 0u, 0u, 0u);
            *(uint4*)&lA[swz_base(row, q)] = v;
        }
    }
    // ---- stage Wa^T ----
    {
        const uint4* Wsrc = (const uint4*)WaT;
        #pragma unroll
        for (int i = 0; i < 8; ++i) {
            int c = tid + 256 * i;
            int row = c >> 4, q = c & 15;
            *(uint4*)&lW[swz_base(row, q)] = Wsrc[c];
        }
    }
    __syncthreads();

    const int am = lane & 15;
    const int kq = (lane >> 4) * 8;             // quad k offset

    f32x4 acc[4][4];
    #pragma unroll
    for (int i = 0; i < 4; ++i)
        #pragma unroll
        for (int j = 0; j < 4; ++j) acc[i][j] = (f32x4){0.f, 0.f, 0.f, 0.f};

    // ---- matmul 1: T = A @ Wa ----
    #pragma unroll
    for (int ks = 0; ks < 4; ++ks) {
        int k0 = ks * 32 + kq;
        bf16x8 af[4], bq[4];
        #pragma unroll
        for (int i = 0; i < 4; ++i)
            af[i] = *(const bf16x8*)&lA[swz_base(wr + i * 16 + am, k0 >> 3)];
        #pragma unroll
        for (int j = 0; j < 4; ++j)
            bq[j] = *(const bf16x8*)&lW[swz_base(wc + j * 16 + am, k0 >> 3)];
        #pragma unroll
        for (int i = 0; i < 4; ++i)
            #pragma unroll
            for (int j = 0; j < 4; ++j)
                acc[i][j] = __builtin_amdgcn_mfma_f32_16x16x32_bf16(af[i], bq[j], acc[i][j], 0, 0, 0);
    }
    __syncthreads();   // all lA/lW reads complete

    // ---- T = relu(acc + ba) -> lA (bf16); restage lW = Wb^T ----
    #pragma unroll
    for (int j = 0; j < 4; ++j) {
        int col = wc + j * 16 + am;
        float bias = ba[col];
        #pragma unroll
        for (int i = 0; i < 4; ++i) {
            int rowb = wr + i * 16 + (lane >> 4) * 4;
            #pragma unroll
            for (int r = 0; r < 4; ++r) {
                float t = acc[i][j][r] + bias;
                t = t > 0.f ? t : 0.f;
                int row = rowb + r;
                lA[swz_base(row, col >> 3) + (col & 7)] = f2bf(t);
            }
        }
    }
    {
        const uint4* Wsrc = (const uint4*)WbT;
        #pragma unroll
        for (int i = 0; i < 8; ++i) {
            int c = tid + 256 * i;
            int row = c >> 4, q = c & 15;
            *(uint4*)&lW[swz_base(row, q)] = Wsrc[c];
        }
    }
    __syncthreads();

    // ---- matmul 2: R = T @ Wb ----
    #pragma unroll
    for (int i = 0; i < 4; ++i)
        #pragma unroll
        for (int j = 0; j < 4; ++j) acc[i][j] = (f32x4){0.f, 0.f, 0.f, 0.f};

    #pragma unroll
    for (int ks = 0; ks < 4; ++ks) {
        int k0 = ks * 32 + kq;
        bf16x8 af[4], bq[4];
        #pragma unroll
        for (int i = 0; i < 4; ++i)
            af[i] = *(const bf16x8*)&lA[swz_base(wr + i * 16 + am, k0 >> 3)];
        #pragma unroll
        for (int j = 0; j < 4; ++j)
            bq[j] = *(const bf16x8*)&lW[swz_base(wc + j * 16 + am, k0 >> 3)];
        #pragma unroll
        for (int i = 0; i < 4; ++i)
            #pragma unroll
            for (int j = 0; j < 4; ++j)
                acc[i][j] = __builtin_amdgcn_mfma_f32_16x16x32_bf16(af[i], bq[j], acc[i][j], 0, 0, 0);
    }

    // ---- epilogue: Y = relu(acc + bb), bf16 ----
    #pragma unroll
    for (int j = 0; j < 4; ++j) {
        int col = wc + j * 16 + am;
        float bias = bb[col];
        #pragma unroll
        for (int i = 0; i < 4; ++i) {
            int rowb = wr + i * 16 + (lane >> 4) * 4;
            #pragma unroll
            for (int r = 0; r < 4; ++r) {
                int row = r0 + rowb + r;
                if (row < N) {
                    float t = acc[i][j][r] + bias;
                    t = t > 0.f ? t : 0.f;
                    Y[(size_t)row * 128 + col] = f2bf(t);
                }
            }
        }
    }
}

// ---------------- pooling: g[batch[n]] += h[n] (bf16 in, fp32 atomic out) ----------------
#define PSTRIP 8
__global__ void k_pool(const unsigned* __restrict__ H, const int* __restrict__ batch,
                       int N, float* __restrict__ G) {
    int wid = (blockIdx.x * blockDim.x + threadIdx.x) >> 6;
    int lane = threadIdx.x & 63;
    int n0 = wid * PSTRIP;
    if (n0 >= N) return;
    int n1 = n0 + PSTRIP; if (n1 > N) n1 = N;
    const size_t fo = (size_t)lane * 2;
    int cur = batch[n0];
    float aL = 0.f, aH = 0.f;
    for (int n = n0; n < n1; ++n) {
        int b = batch[n];
        if (b != cur) {
            atomicAdd(&G[(size_t)cur * 128 + fo], aL);
            atomicAdd(&G[(size_t)cur * 128 + fo + 1], aH);
            aL = 0.f; aH = 0.f;
            cur = b;
        }
        unsigned v = H[(size_t)n * 64 + lane];
        aL += bf_lo(v);
        aH += bf_hi(v);
    }
    atomicAdd(&G[(size_t)cur * 128 + fo], aL);
    atomicAdd(&G[(size_t)cur * 128 + fo + 1], aH);
}

// ---------------- head: out = log_softmax(relu(g@Wl1+bl1)@Wl2+bl2) ----------------
__global__ void k_head(const float* __restrict__ G,
                       const float* __restrict__ Wl1, const float* __restrict__ bl1,
                       const float* __restrict__ Wl2, const float* __restrict__ bl2,
                       int C, float* __restrict__ out) {
    __shared__ float sg[128];
    __shared__ float sh[128];
    __shared__ float sl[16];
    int row = blockIdx.x;
    int t = threadIdx.x;
    sg[t] = G[(size_t)row * 128 + t];
    __syncthreads();
    float a = bl1[t];
    for (int k = 0; k < 128; ++k) a += sg[k] * Wl1[k * 128 + t];
    sh[t] = a > 0.f ? a : 0.f;
    __syncthreads();
    if (t < C) {
        float l = bl2[t];
        for (int k = 0; k < 128; ++k) l += sh[k] * Wl2[k * C + t];
        sl[t] = l;
    }
    __syncthreads();
    if (t < C) {
        float m = -1e30f;
        for (int j = 0; j < C; ++j) m = fmaxf(m, sl[j]);
        float s = 0.f;
        for (int j = 0; j < C; ++j) s += __expf(sl[j] - m);
        out[(size_t)row * C + t] = sl[t] - m - __logf(s);
    }
}

extern "C" void kernel_launch(void* const* d_in, const int* in_sizes, int n_in,
                              void* d_out, int out_size, void* d_ws, size_t ws_size,
                              hipStream_t stream) {
    const float* x    = (const float*)d_in[0];
    const int*   ei   = (const int*)d_in[1];     // [2][E]
    const int*   batch= (const int*)d_in[2];
    const float* W1a  = (const float*)d_in[3];
    const float* b1a  = (const float*)d_in[4];
    const float* W1b  = (const float*)d_in[5];
    const float* b1b  = (const float*)d_in[6];
    const float* W2a  = (const float*)d_in[7];
    const float* b2a  = (const float*)d_in[8];
    const float* W2b  = (const float*)d_in[9];
    const float* b2b  = (const float*)d_in[10];
    const float* Wl1  = (const float*)d_in[11];
    const float* bl1  = (const float*)d_in[12];
    const float* Wl2  = (const float*)d_in[13];
    const float* bl2  = (const float*)d_in[14];
    float* out = (float*)d_out;

    const int N = in_sizes[2];
    const int E = in_sizes[1] / 2;
    const int C = in_sizes[13] / 128;

    char* p = (char*)d_ws;
    auto alloc = [&](size_t bytes) {
        char* r = p;
        p += (bytes + 255) & ~(size_t)255;
        return r;
    };
    unsigned* xb = (unsigned*)alloc((size_t)N * 64 * 4);          // x in bf16
    unsigned* hA = (unsigned*)alloc((size_t)N * 64 * 4);          // agg output / conv1 out (bf16)
    unsigned* hB = (unsigned*)alloc((size_t)N * 64 * 4);          // conv output (bf16)
    float* g   = (float*)alloc((size_t)NUM_GRAPHS * 128 * 4);
    int* deg   = (int*)alloc((size_t)N * 4);
    int* excl  = (int*)alloc((size_t)N * 4);
    int* rp    = (int*)alloc((size_t)(N + 1) * 4);
    int* rank  = (int*)alloc((size_t)E * 4);
    int* bsum  = (int*)alloc(4096);
    int* srcs  = (int*)alloc((size_t)E * 4);
    unsigned short* wt = (unsigned short*)alloc((size_t)4 * 16384 * 2);
    (void)ws_size; (void)n_in; (void)out_size;

    const int nb = (N + 255) / 256;
    const int eb = (E + 255) / 256;

    hipMemsetAsync(deg, 0, (size_t)N * 4, stream);
    hipMemsetAsync(g, 0, (size_t)NUM_GRAPHS * 128 * 4, stream);

    // pre-pass: deg+rank histogram and x->bf16 in one dispatch
    k_pre<<<eb + 4096, 256, 0, stream>>>(ei + E, E, deg, rank, x, N * 32, xb, eb);
    // scans -> row pointers
    k_scan1<<<nb, 256, 0, stream>>>(deg, N, excl, bsum);
    k_scan2<<<1, 1024, 0, stream>>>(bsum, nb);
    k_scan3<<<nb, 256, 0, stream>>>(excl, bsum, N, E, rp);
    k_fill3<<<2048, 256, 0, stream>>>(ei, rank, E, rp, srcs);
    // bf16 weights (all four in one dispatch)
    k_prepw4<<<256, 256, 0, stream>>>(W1a, W1b, W2a, W2b, wt);

    const int mb = (N + 127) / 128;
    const int qw = (N + 3) / 4;          // quarter-wave agg: 4 nodes per wave
    const int qb = (qw + 3) / 4;         // 4 waves per block

    // conv1
    k_aggq<<<qb, 256, 0, stream>>>((const uint4*)xb, rp, srcs, N, (uint4*)hA);
    k_mlp<<<mb, 256, 0, stream>>>((const unsigned short*)hA, N, wt, b1a, wt + 16384, b1b,
                                  (unsigned short*)hB);
    // conv2
    k_aggq<<<qb, 256, 0, stream>>>((const uint4*)hB, rp, srcs, N, (uint4*)hA);
    k_mlp<<<mb, 256, 0, stream>>>((const unsigned short*)hA, N, wt + 2 * 16384, b2a,
                                  wt + 3 * 16384, b2b, (unsigned short*)hB);

    // pool + head
    const int pw = (N + PSTRIP - 1) / PSTRIP;
    const int pb = (pw + 3) / 4;
    k_pool<<<pb, 256, 0, stream>>>(hB, batch, N, g);
    k_head<<<NUM_GRAPHS, 128, 0, stream>>>(g, Wl1, bl1, Wl2, bl2, C, out);
}

// Round 5
// 419.757 us; speedup vs baseline: 1.5560x; 1.0462x over previous
//
#include <hip/hip_runtime.h>
#include <hip/hip_bf16.h>
#include <math.h>

#define NUM_GRAPHS 1024

typedef __attribute__((ext_vector_type(8))) short bf16x8;
typedef __attribute__((ext_vector_type(4))) float f32x4;

static __device__ __forceinline__ unsigned short f2bf(float f) {
    union { float f; unsigned u; } v; v.f = f;
    unsigned r = v.u + 0x7fffu + ((v.u >> 16) & 1u);   // round-to-nearest-even
    return (unsigned short)(r >> 16);
}
static __device__ __forceinline__ float bf_lo(unsigned u) { return __uint_as_float(u << 16); }
static __device__ __forceinline__ float bf_hi(unsigned u) { return __uint_as_float(u & 0xffff0000u); }

// ---------------- pre-pass: deg histogram + per-edge rank, x->bf16, zero G ----------------
__global__ void k_pre(const int* __restrict__ eiDst, int E,
                      int* __restrict__ deg, int* __restrict__ rank,
                      const float* __restrict__ x, int n4, unsigned* __restrict__ xb,
                      float* __restrict__ G, int eb) {
    if ((int)blockIdx.x < eb) {
        int e = blockIdx.x * 256 + threadIdx.x;
        if (e < E) rank[e] = atomicAdd(&deg[eiDst[e]], 1);
    } else if ((int)blockIdx.x < eb + 4096) {
        int i = (blockIdx.x - eb) * 256 + threadIdx.x;
        int stride = 4096 * 256;
        const float4* x4 = (const float4*)x;
        for (; i < n4; i += stride) {
            float4 v = x4[i];
            unsigned lo = (unsigned)f2bf(v.x) | ((unsigned)f2bf(v.y) << 16);
            unsigned hi = (unsigned)f2bf(v.z) | ((unsigned)f2bf(v.w) << 16);
            ((uint2*)xb)[i] = make_uint2(lo, hi);
        }
    } else {
        // zero G: NUM_GRAPHS*128 floats = 32768 float4
        int i = (blockIdx.x - eb - 4096) * 256 + threadIdx.x;
        float4* G4 = (float4*)G;
        for (; i < NUM_GRAPHS * 32; i += 64 * 256)
            G4[i] = make_float4(0.f, 0.f, 0.f, 0.f);
    }
}

// ---------------- scans ----------------
__global__ void k_scan1(const int* __restrict__ deg, int N,
                        int* __restrict__ excl, int* __restrict__ bsum) {
    __shared__ int s[256];
    int i = blockIdx.x * 256 + threadIdx.x;
    int v = (i < N) ? deg[i] : 0;
    s[threadIdx.x] = v;
    __syncthreads();
    for (int off = 1; off < 256; off <<= 1) {
        int t = (threadIdx.x >= off) ? s[threadIdx.x - off] : 0;
        __syncthreads();
        s[threadIdx.x] += t;
        __syncthreads();
    }
    if (i < N) excl[i] = s[threadIdx.x] - v;
    if (threadIdx.x == 255) bsum[blockIdx.x] = s[255];
}

// Each block redundantly scans bsum[0..nb) in LDS (nb <= 512), then applies
// its own exclusive offset to produce rp. Fuses old scan2+scan3.
__global__ void k_scan23(const int* __restrict__ excl, const int* __restrict__ bsum,
                         int nb, int N, int E, int* __restrict__ rp) {
    __shared__ int s[512];
    const int t = threadIdx.x;
    for (int k = t; k < 512; k += 256) s[k] = (k < nb) ? bsum[k] : 0;
    __syncthreads();
    #pragma unroll
    for (int off = 1; off < 512; off <<= 1) {
        int a = (t >= off) ? s[t - off] : 0;
        int b = s[t + 256 - off];
        __syncthreads();
        s[t] += a;
        s[t + 256] += b;
        __syncthreads();
    }
    const int myIncl = s[blockIdx.x];
    const int myOwn = bsum[blockIdx.x];
    const int off_b = myIncl - myOwn;   // exclusive prefix for this block
    int i = blockIdx.x * 256 + t;
    if (i < N) rp[i] = excl[i] + off_b;
    if (i == 0) rp[N] = E;
}

// ---------------- fill (3 dst-range passes) + weight prep in one dispatch ----------------
#define FILL_PASSES 3
#define FILL_RANGE 33334
#define FILL_BLOCKS 2048
__global__ void k_fillprep(const int* __restrict__ ei, const int* __restrict__ rank,
                           int E, const int* __restrict__ rp, int* __restrict__ srcs,
                           const float* __restrict__ W0, const float* __restrict__ W1,
                           const float* __restrict__ W2, const float* __restrict__ W3,
                           unsigned short* __restrict__ wt) {
    if ((int)blockIdx.x < FILL_BLOCKS) {
        const int tid0 = blockIdx.x * 256 + threadIdx.x;
        const int stride = FILL_BLOCKS * 256;
        for (int pass = 0; pass < FILL_PASSES; ++pass) {
            const int lo = pass * FILL_RANGE;
            const int hi = lo + FILL_RANGE;
            for (int e = tid0; e < E; e += stride) {
                int d = ei[(size_t)E + e];
                if (d >= lo && d < hi) {
                    srcs[rp[d] + rank[e]] = ei[e];
                }
            }
        }
    } else {
        int lb = blockIdx.x - FILL_BLOCKS;          // 0..255
        int b = lb >> 6;                            // 0..3
        const float* W = (b == 0) ? W0 : (b == 1) ? W1 : (b == 2) ? W2 : W3;
        int idx = (lb & 63) * 256 + threadIdx.x;    // 0..16383
        int k = idx >> 7, n = idx & 127;
        wt[b * 16384 + n * 128 + k] = f2bf(W[idx]);
    }
}

// ---------------- quarter-wave aggregation (bf16 in/out, fp32 accumulate) ----------------
__device__ __forceinline__ void acc8(float* a, uint4 v) {
    a[0] += bf_lo(v.x); a[1] += bf_hi(v.x);
    a[2] += bf_lo(v.y); a[3] += bf_hi(v.y);
    a[4] += bf_lo(v.z); a[5] += bf_hi(v.z);
    a[6] += bf_lo(v.w); a[7] += bf_hi(v.w);
}

__global__ __launch_bounds__(256, 8)
void k_aggq(const uint4* __restrict__ H4, const int* __restrict__ rp,
            const int* __restrict__ srcs, int N, uint4* __restrict__ out) {
    int gw = (blockIdx.x * blockDim.x + threadIdx.x) >> 6;   // wave id
    int lane = threadIdx.x & 63;
    int q = lane >> 4, ql = lane & 15;                       // quarter, lane-in-quarter
    int n = gw * 4 + q;
    if (gw * 4 >= N) return;
    bool act = (n < N);
    int nc = act ? n : 0;
    uint4 s0 = H4[(size_t)nc * 16 + ql];
    float a[8];
    a[0] = bf_lo(s0.x); a[1] = bf_hi(s0.x);
    a[2] = bf_lo(s0.y); a[3] = bf_hi(s0.y);
    a[4] = bf_lo(s0.z); a[5] = bf_hi(s0.z);
    a[6] = bf_lo(s0.w); a[7] = bf_hi(s0.w);
    int j = act ? rp[nc] : 0;
    int e = act ? rp[nc + 1] : 0;
    while (j + 4 <= e) {
        int i0 = srcs[j], i1 = srcs[j + 1], i2 = srcs[j + 2], i3 = srcs[j + 3];
        uint4 v0 = H4[(size_t)i0 * 16 + ql];
        uint4 v1 = H4[(size_t)i1 * 16 + ql];
        uint4 v2 = H4[(size_t)i2 * 16 + ql];
        uint4 v3 = H4[(size_t)i3 * 16 + ql];
        acc8(a, v0); acc8(a, v1); acc8(a, v2); acc8(a, v3);
        j += 4;
    }
    while (j < e) {
        uint4 v = H4[(size_t)srcs[j] * 16 + ql];
        acc8(a, v);
        ++j;
    }
    if (act) {
        uint4 o;
        o.x = (unsigned)f2bf(a[0]) | ((unsigned)f2bf(a[1]) << 16);
        o.y = (unsigned)f2bf(a[2]) | ((unsigned)f2bf(a[3]) << 16);
        o.z = (unsigned)f2bf(a[4]) | ((unsigned)f2bf(a[5]) << 16);
        o.w = (unsigned)f2bf(a[6]) | ((unsigned)f2bf(a[7]) << 16);
        out[(size_t)n * 16 + ql] = o;
    }
}

// ---------------- fused 2-layer MLP; POOL variant pools into G instead of writing Y ----------------
// XOR-chunk swizzle: (row, chunk of 8 elems) -> element row*128 + ((chunk ^ (row&7))*8)
__device__ __forceinline__ int swz_base(int row, int chunk) {
    return row * 128 + ((chunk ^ (row & 7)) << 3);
}

template <bool POOL>
__global__ __launch_bounds__(256, 2)
void k_mlp(const unsigned short* __restrict__ U, int N,
           const unsigned short* __restrict__ WaT, const float* __restrict__ ba,
           const unsigned short* __restrict__ WbT, const float* __restrict__ bb,
           unsigned short* __restrict__ Y,
           const int* __restrict__ batch, float* __restrict__ G) {
    __shared__ unsigned short lA[128 * 128];   // 32 KB: A tile, then T tile, then R tile
    __shared__ unsigned short lW[128 * 128];   // 32 KB: Wa^T, then Wb^T
    __shared__ int bs[128];

    const int tid = threadIdx.x;
    const int lane = tid & 63;
    const int w = tid >> 6;              // wave 0..3
    const int wr = (w >> 1) * 64;        // wave row offset
    const int wc = (w & 1) * 64;         // wave col offset
    const int r0 = blockIdx.x * 128;

    // ---- stage A: bf16 global -> LDS (swizzled), 16B = one 8-elem chunk ----
    {
        const uint4* U4 = (const uint4*)U;
        #pragma unroll
        for (int i = 0; i < 8; ++i) {
            int c = tid + 256 * i;              // 0..2047
            int row = c >> 4, q = c & 15;
            uint4 v = (r0 + row < N) ? U4[(size_t)(r0 + row) * 16 + q]
                                     : make_uint4(0u, 0u, 0u, 0u);
            *(uint4*)&lA[swz_base(row, q)] = v;
        }
    }
    // ---- stage Wa^T ----
    {
        const uint4* Wsrc = (const uint4*)WaT;
        #pragma unroll
        for (int i = 0; i < 8; ++i) {
            int c = tid + 256 * i;
            int row = c >> 4, q = c & 15;
            *(uint4*)&lW[swz_base(row, q)] = Wsrc[c];
        }
    }
    __syncthreads();

    const int am = lane & 15;
    const int kq = (lane >> 4) * 8;             // quad k offset

    f32x4 acc[4][4];
    #pragma unroll
    for (int i = 0; i < 4; ++i)
        #pragma unroll
        for (int j = 0; j < 4; ++j) acc[i][j] = (f32x4){0.f, 0.f, 0.f, 0.f};

    // ---- matmul 1: T = A @ Wa ----
    #pragma unroll
    for (int ks = 0; ks < 4; ++ks) {
        int k0 = ks * 32 + kq;
        bf16x8 af[4], bq[4];
        #pragma unroll
        for (int i = 0; i < 4; ++i)
            af[i] = *(const bf16x8*)&lA[swz_base(wr + i * 16 + am, k0 >> 3)];
        #pragma unroll
        for (int j = 0; j < 4; ++j)
            bq[j] = *(const bf16x8*)&lW[swz_base(wc + j * 16 + am, k0 >> 3)];
        #pragma unroll
        for (int i = 0; i < 4; ++i)
            #pragma unroll
            for (int j = 0; j < 4; ++j)
                acc[i][j] = __builtin_amdgcn_mfma_f32_16x16x32_bf16(af[i], bq[j], acc[i][j], 0, 0, 0);
    }
    __syncthreads();   // all lA/lW reads complete

    // ---- T = relu(acc + ba) -> lA (bf16); restage lW = Wb^T ----
    #pragma unroll
    for (int j = 0; j < 4; ++j) {
        int col = wc + j * 16 + am;
        float bias = ba[col];
        #pragma unroll
        for (int i = 0; i < 4; ++i) {
            int rowb = wr + i * 16 + (lane >> 4) * 4;
            #pragma unroll
            for (int r = 0; r < 4; ++r) {
                float t = acc[i][j][r] + bias;
                t = t > 0.f ? t : 0.f;
                int row = rowb + r;
                lA[swz_base(row, col >> 3) + (col & 7)] = f2bf(t);
            }
        }
    }
    {
        const uint4* Wsrc = (const uint4*)WbT;
        #pragma unroll
        for (int i = 0; i < 8; ++i) {
            int c = tid + 256 * i;
            int row = c >> 4, q = c & 15;
            *(uint4*)&lW[swz_base(row, q)] = Wsrc[c];
        }
    }
    __syncthreads();

    // ---- matmul 2: R = T @ Wb ----
    #pragma unroll
    for (int i = 0; i < 4; ++i)
        #pragma unroll
        for (int j = 0; j < 4; ++j) acc[i][j] = (f32x4){0.f, 0.f, 0.f, 0.f};

    #pragma unroll
    for (int ks = 0; ks < 4; ++ks) {
        int k0 = ks * 32 + kq;
        bf16x8 af[4], bq[4];
        #pragma unroll
        for (int i = 0; i < 4; ++i)
            af[i] = *(const bf16x8*)&lA[swz_base(wr + i * 16 + am, k0 >> 3)];
        #pragma unroll
        for (int j = 0; j < 4; ++j)
            bq[j] = *(const bf16x8*)&lW[swz_base(wc + j * 16 + am, k0 >> 3)];
        #pragma unroll
        for (int i = 0; i < 4; ++i)
            #pragma unroll
            for (int j = 0; j < 4; ++j)
                acc[i][j] = __builtin_amdgcn_mfma_f32_16x16x32_bf16(af[i], bq[j], acc[i][j], 0, 0, 0);
    }

    if (!POOL) {
        // ---- epilogue: Y = relu(acc + bb), bf16 ----
        #pragma unroll
        for (int j = 0; j < 4; ++j) {
            int col = wc + j * 16 + am;
            float bias = bb[col];
            #pragma unroll
            for (int i = 0; i < 4; ++i) {
                int rowb = wr + i * 16 + (lane >> 4) * 4;
                #pragma unroll
                for (int r = 0; r < 4; ++r) {
                    int row = r0 + rowb + r;
                    if (row < N) {
                        float t = acc[i][j][r] + bias;
                        t = t > 0.f ? t : 0.f;
                        Y[(size_t)row * 128 + col] = f2bf(t);
                    }
                }
            }
        }
    } else {
        // ---- epilogue: R = relu(acc+bb) -> LDS (bf16), then segmented pool into G ----
        __syncthreads();   // matmul-2 lA reads complete before overwrite
        #pragma unroll
        for (int j = 0; j < 4; ++j) {
            int col = wc + j * 16 + am;
            float bias = bb[col];
            #pragma unroll
            for (int i = 0; i < 4; ++i) {
                int rowb = wr + i * 16 + (lane >> 4) * 4;
                #pragma unroll
                for (int r = 0; r < 4; ++r) {
                    float t = acc[i][j][r] + bias;
                    t = t > 0.f ? t : 0.f;
                    int row = rowb + r;
                    lA[swz_base(row, col >> 3) + (col & 7)] = f2bf(t);
                }
            }
        }
        if (tid < 128) bs[tid] = (r0 + tid < N) ? batch[r0 + tid] : -1;
        __syncthreads();
        // thread t: column t&127, row half t>>7; batch is sorted -> run accumulate
        const int col = tid & 127;
        const int half = tid >> 7;
        const int rbeg = half * 64, rend = rbeg + 64;
        float pacc = 0.f;
        int cur = bs[rbeg];
        for (int row = rbeg; row < rend; ++row) {
            int b = bs[row];
            if (b != cur) {
                if (cur >= 0) atomicAdd(&G[(size_t)cur * 128 + col], pacc);
                pacc = 0.f;
                cur = b;
            }
            unsigned short u = lA[swz_base(row, col >> 3) + (col & 7)];
            pacc += __uint_as_float((unsigned)u << 16);
        }
        if (cur >= 0) atomicAdd(&G[(size_t)cur * 128 + col], pacc);
    }
}

// ---------------- head: out = log_softmax(relu(g@Wl1+bl1)@Wl2+bl2) ----------------
__global__ void k_head(const float* __restrict__ G,
                       const float* __restrict__ Wl1, const float* __restrict__ bl1,
                       const float* __restrict__ Wl2, const float* __restrict__ bl2,
                       int C, float* __restrict__ out) {
    __shared__ float sg[128];
    __shared__ float sh[128];
    __shared__ float sl[16];
    int row = blockIdx.x;
    int t = threadIdx.x;
    sg[t] = G[(size_t)row * 128 + t];
    __syncthreads();
    float a = bl1[t];
    for (int k = 0; k < 128; ++k) a += sg[k] * Wl1[k * 128 + t];
    sh[t] = a > 0.f ? a : 0.f;
    __syncthreads();
    if (t < C) {
        float l = bl2[t];
        for (int k = 0; k < 128; ++k) l += sh[k] * Wl2[k * C + t];
        sl[t] = l;
    }
    __syncthreads();
    if (t < C) {
        float m = -1e30f;
        for (int j = 0; j < C; ++j) m = fmaxf(m, sl[j]);
        float s = 0.f;
        for (int j = 0; j < C; ++j) s += __expf(sl[j] - m);
        out[(size_t)row * C + t] = sl[t] - m - __logf(s);
    }
}

extern "C" void kernel_launch(void* const* d_in, const int* in_sizes, int n_in,
                              void* d_out, int out_size, void* d_ws, size_t ws_size,
                              hipStream_t stream) {
    const float* x    = (const float*)d_in[0];
    const int*   ei   = (const int*)d_in[1];     // [2][E]
    const int*   batch= (const int*)d_in[2];
    const float* W1a  = (const float*)d_in[3];
    const float* b1a  = (const float*)d_in[4];
    const float* W1b  = (const float*)d_in[5];
    const float* b1b  = (const float*)d_in[6];
    const float* W2a  = (const float*)d_in[7];
    const float* b2a  = (const float*)d_in[8];
    const float* W2b  = (const float*)d_in[9];
    const float* b2b  = (const float*)d_in[10];
    const float* Wl1  = (const float*)d_in[11];
    const float* bl1  = (const float*)d_in[12];
    const float* Wl2  = (const float*)d_in[13];
    const float* bl2  = (const float*)d_in[14];
    float* out = (float*)d_out;

    const int N = in_sizes[2];
    const int E = in_sizes[1] / 2;
    const int C = in_sizes[13] / 128;

    char* p = (char*)d_ws;
    auto alloc = [&](size_t bytes) {
        char* r = p;
        p += (bytes + 255) & ~(size_t)255;
        return r;
    };
    unsigned* xb = (unsigned*)alloc((size_t)N * 64 * 4);          // x in bf16
    unsigned* hA = (unsigned*)alloc((size_t)N * 64 * 4);          // agg out (bf16)
    unsigned* hB = (unsigned*)alloc((size_t)N * 64 * 4);          // conv1 out (bf16)
    float* g   = (float*)alloc((size_t)NUM_GRAPHS * 128 * 4);
    int* deg   = (int*)alloc((size_t)N * 4);
    int* excl  = (int*)alloc((size_t)N * 4);
    int* rp    = (int*)alloc((size_t)(N + 1) * 4);
    int* rank  = (int*)alloc((size_t)E * 4);
    int* bsum  = (int*)alloc(4096);
    int* srcs  = (int*)alloc((size_t)E * 4);
    unsigned short* wt = (unsigned short*)alloc((size_t)4 * 16384 * 2);
    (void)ws_size; (void)n_in; (void)out_size;

    const int nb = (N + 255) / 256;
    const int eb = (E + 255) / 256;

    hipMemsetAsync(deg, 0, (size_t)N * 4, stream);

    // pre-pass: deg+rank histogram, x->bf16, zero G — one dispatch
    k_pre<<<eb + 4096 + 64, 256, 0, stream>>>(ei + E, E, deg, rank, x, N * 32, xb, g, eb);
    // scans -> row pointers (2 dispatches)
    k_scan1<<<nb, 256, 0, stream>>>(deg, N, excl, bsum);
    k_scan23<<<nb, 256, 0, stream>>>(excl, bsum, nb, N, E, rp);
    // fill + weight prep in one dispatch
    k_fillprep<<<FILL_BLOCKS + 256, 256, 0, stream>>>(ei, rank, E, rp, srcs,
                                                      W1a, W1b, W2a, W2b, wt);

    const int mb = (N + 127) / 128;
    const int qw = (N + 3) / 4;          // quarter-wave agg: 4 nodes per wave
    const int qb = (qw + 3) / 4;         // 4 waves per block

    // conv1
    k_aggq<<<qb, 256, 0, stream>>>((const uint4*)xb, rp, srcs, N, (uint4*)hA);
    k_mlp<false><<<mb, 256, 0, stream>>>((const unsigned short*)hA, N, wt, b1a,
                                         wt + 16384, b1b, (unsigned short*)hB,
                                         nullptr, nullptr);
    // conv2 (+ fused global_add_pool into G)
    k_aggq<<<qb, 256, 0, stream>>>((const uint4*)hB, rp, srcs, N, (uint4*)hA);
    k_mlp<true><<<mb, 256, 0, stream>>>((const unsigned short*)hA, N, wt + 2 * 16384, b2a,
                                        wt + 3 * 16384, b2b, nullptr,
                                        batch, g);
    // head
    k_head<<<NUM_GRAPHS, 128, 0, stream>>>(g, Wl1, bl1, Wl2, bl2, C, out);
}

// Round 6
// 411.925 us; speedup vs baseline: 1.5856x; 1.0190x over previous
//
#include <hip/hip_runtime.h>
#include <hip/hip_bf16.h>
#include <math.h>

#define NUM_GRAPHS 1024
#define NBLK 512          // edge-blocks in counting-sort passes

typedef __attribute__((ext_vector_type(8))) short bf16x8;
typedef __attribute__((ext_vector_type(4))) float f32x4;

static __device__ __forceinline__ unsigned short f2bf(float f) {
    union { float f; unsigned u; } v; v.f = f;
    unsigned r = v.u + 0x7fffu + ((v.u >> 16) & 1u);   // round-to-nearest-even
    return (unsigned short)(r >> 16);
}
static __device__ __forceinline__ float bf_lo(unsigned u) { return __uint_as_float(u << 16); }
static __device__ __forceinline__ float bf_hi(unsigned u) { return __uint_as_float(u & 0xffff0000u); }

// exclusive scan of tot[0..nbuck) into LDS bb[0..nbuck] (bb[nbuck]=grand total).
// 256 threads, nbuck <= 1024. tmp is 256-int LDS scratch.
static __device__ void scan_tot(const int* __restrict__ tot, int nbuck,
                                int* bb, int* tmp) {
    const int t = threadIdx.x;
    int v[4];
    int lsum = 0;
    #pragma unroll
    for (int j = 0; j < 4; ++j) {
        int idx = 4 * t + j;
        v[j] = (idx < nbuck) ? tot[idx] : 0;
        lsum += v[j];
    }
    tmp[t] = lsum;
    __syncthreads();
    for (int off = 1; off < 256; off <<= 1) {
        int a = (t >= off) ? tmp[t - off] : 0;
        __syncthreads();
        tmp[t] += a;
        __syncthreads();
    }
    int run = tmp[t] - lsum;   // exclusive prefix of this thread's chunk
    #pragma unroll
    for (int j = 0; j < 4; ++j) {
        int idx = 4 * t + j;
        if (idx < nbuck) bb[idx] = run;
        run += v[j];
    }
    if (t == 255) bb[nbuck] = tmp[255];
    __syncthreads();
}

// ---------------- P1 (+ x->bf16 + zero G): per-block LDS bucket histogram ----------------
__global__ void k_pre(const int* __restrict__ eiDst, int E, int epb, int nbuck,
                      int* __restrict__ cnt,
                      const float* __restrict__ x, int n4, unsigned* __restrict__ xb,
                      float* __restrict__ G) {
    if ((int)blockIdx.x < NBLK) {
        __shared__ int hist[1024];
        const int t = threadIdx.x;
        for (int i = t; i < 1024; i += 256) hist[i] = 0;
        __syncthreads();
        const int kb = blockIdx.x;
        const int e0 = kb * epb;
        const int e1 = min(E, e0 + epb);
        for (int e = e0 + t; e < e1; e += 256) atomicAdd(&hist[eiDst[e] >> 7], 1);
        __syncthreads();
        for (int b = t; b < nbuck; b += 256) cnt[(size_t)b * NBLK + kb] = hist[b];
    } else if ((int)blockIdx.x < NBLK + 2048) {
        int i = (blockIdx.x - NBLK) * 256 + threadIdx.x;
        const int stride = 2048 * 256;
        const float4* x4 = (const float4*)x;
        for (; i < n4; i += stride) {
            float4 v = x4[i];
            unsigned lo = (unsigned)f2bf(v.x) | ((unsigned)f2bf(v.y) << 16);
            unsigned hi = (unsigned)f2bf(v.z) | ((unsigned)f2bf(v.w) << 16);
            ((uint2*)xb)[i] = make_uint2(lo, hi);
        }
    } else {
        int i = (blockIdx.x - NBLK - 2048) * 256 + threadIdx.x;
        float4* G4 = (float4*)G;
        for (; i < NUM_GRAPHS * 32; i += 64 * 256)
            G4[i] = make_float4(0.f, 0.f, 0.f, 0.f);
    }
}

// ---------------- column scan: pref[b][k] = sum_{k'<k} cnt[b][k'], tot[b] ----------------
__global__ void k_colscan(const int* __restrict__ cnt, int nbuck,
                          int* __restrict__ pref, int* __restrict__ tot) {
    int b = blockIdx.x * 256 + threadIdx.x;
    if (b >= nbuck) return;
    const int* c = cnt + (size_t)b * NBLK;
    int* pf = pref + (size_t)b * NBLK;
    int run = 0;
    #pragma unroll 4
    for (int k = 0; k < NBLK; ++k) { pf[k] = run; run += c[k]; }
    tot[b] = run;
}

// ---------------- P2: scatter edges into bucket-sorted ebuf (packed d7|src) ----------------
__global__ void k_scatter(const int* __restrict__ eiSrc, const int* __restrict__ eiDst,
                          int E, int epb, const int* __restrict__ pref,
                          const int* __restrict__ tot, int nbuck,
                          unsigned* __restrict__ ebuf) {
    __shared__ int bb[1025];
    __shared__ int tmp[256];
    __shared__ int cur[1024];
    const int t = threadIdx.x;
    const int kb = blockIdx.x;
    scan_tot(tot, nbuck, bb, tmp);
    for (int b = t; b < nbuck; b += 256) cur[b] = bb[b] + pref[(size_t)b * NBLK + kb];
    __syncthreads();
    const int e0 = kb * epb;
    const int e1 = min(E, e0 + epb);
    for (int e = e0 + t; e < e1; e += 256) {
        int d = eiDst[e];
        int s = eiSrc[e];
        int pos = atomicAdd(&cur[d >> 7], 1);
        ebuf[pos] = (unsigned)s | ((unsigned)(d & 127) << 25);
    }
}

// ---------------- P3: per-bucket fine sort -> rp + srcs; extra blocks do weight prep ----------------
__global__ void k_bucket(const unsigned* __restrict__ ebuf, const int* __restrict__ tot,
                         int nbuck, int N, int* __restrict__ rp, int* __restrict__ srcs,
                         const float* __restrict__ W0, const float* __restrict__ W1,
                         const float* __restrict__ W2, const float* __restrict__ W3,
                         unsigned short* __restrict__ wt) {
    if ((int)blockIdx.x >= nbuck) {
        int lb = blockIdx.x - nbuck;                // 0..255
        int b4 = lb >> 6;                           // 0..3
        const float* W = (b4 == 0) ? W0 : (b4 == 1) ? W1 : (b4 == 2) ? W2 : W3;
        int idx = (lb & 63) * 256 + threadIdx.x;    // 0..16383
        int k = idx >> 7, n = idx & 127;
        wt[b4 * 16384 + n * 128 + k] = f2bf(W[idx]);
        return;
    }
    __shared__ int bb[1025];
    __shared__ int tmp[256];
    __shared__ int h[128];
    __shared__ int cur[128];
    const int t = threadIdx.x;
    const int b = blockIdx.x;
    scan_tot(tot, nbuck, bb, tmp);
    const int base = bb[b];
    const int cntb = bb[b + 1] - base;
    if (t < 128) h[t] = 0;
    __syncthreads();
    for (int i = t; i < cntb; i += 256) atomicAdd(&h[ebuf[base + i] >> 25], 1);
    __syncthreads();
    int c0 = (t < 128) ? h[t] : 0;
    for (int off = 1; off < 128; off <<= 1) {
        int a = (t >= off && t < 128) ? h[t - off] : 0;
        __syncthreads();
        if (t < 128) h[t] += a;
        __syncthreads();
    }
    if (t < 128) {
        int excl = h[t] - c0;
        cur[t] = excl;
        int d = (b << 7) + t;
        if (d < N) rp[d] = base + excl;
        if (d == N) rp[N] = base + excl;   // == E (all edges precede)
    }
    __syncthreads();
    for (int i = t; i < cntb; i += 256) {
        unsigned pck = ebuf[base + i];
        int pos = atomicAdd(&cur[pck >> 25], 1);
        srcs[base + pos] = (int)(pck & 0x01FFFFFFu);
    }
}

// ---------------- quarter-wave aggregation (bf16 in/out, fp32 accumulate) ----------------
__device__ __forceinline__ void acc8(float* a, uint4 v) {
    a[0] += bf_lo(v.x); a[1] += bf_hi(v.x);
    a[2] += bf_lo(v.y); a[3] += bf_hi(v.y);
    a[4] += bf_lo(v.z); a[5] += bf_hi(v.z);
    a[6] += bf_lo(v.w); a[7] += bf_hi(v.w);
}

__global__ __launch_bounds__(256, 8)
void k_aggq(const uint4* __restrict__ H4, const int* __restrict__ rp,
            const int* __restrict__ srcs, int N, uint4* __restrict__ out) {
    int gw = (blockIdx.x * blockDim.x + threadIdx.x) >> 6;   // wave id
    int lane = threadIdx.x & 63;
    int q = lane >> 4, ql = lane & 15;                       // quarter, lane-in-quarter
    int n = gw * 4 + q;
    if (gw * 4 >= N) return;
    bool act = (n < N);
    int nc = act ? n : 0;
    uint4 s0 = H4[(size_t)nc * 16 + ql];
    float a[8];
    a[0] = bf_lo(s0.x); a[1] = bf_hi(s0.x);
    a[2] = bf_lo(s0.y); a[3] = bf_hi(s0.y);
    a[4] = bf_lo(s0.z); a[5] = bf_hi(s0.z);
    a[6] = bf_lo(s0.w); a[7] = bf_hi(s0.w);
    int j = act ? rp[nc] : 0;
    int e = act ? rp[nc + 1] : 0;
    while (j + 4 <= e) {
        int i0 = srcs[j], i1 = srcs[j + 1], i2 = srcs[j + 2], i3 = srcs[j + 3];
        uint4 v0 = H4[(size_t)i0 * 16 + ql];
        uint4 v1 = H4[(size_t)i1 * 16 + ql];
        uint4 v2 = H4[(size_t)i2 * 16 + ql];
        uint4 v3 = H4[(size_t)i3 * 16 + ql];
        acc8(a, v0); acc8(a, v1); acc8(a, v2); acc8(a, v3);
        j += 4;
    }
    while (j < e) {
        uint4 v = H4[(size_t)srcs[j] * 16 + ql];
        acc8(a, v);
        ++j;
    }
    if (act) {
        uint4 o;
        o.x = (unsigned)f2bf(a[0]) | ((unsigned)f2bf(a[1]) << 16);
        o.y = (unsigned)f2bf(a[2]) | ((unsigned)f2bf(a[3]) << 16);
        o.z = (unsigned)f2bf(a[4]) | ((unsigned)f2bf(a[5]) << 16);
        o.w = (unsigned)f2bf(a[6]) | ((unsigned)f2bf(a[7]) << 16);
        out[(size_t)n * 16 + ql] = o;
    }
}

// ---------------- fused 2-layer MLP; POOL variant pools into G instead of writing Y ----------------
// XOR-chunk swizzle: (row, chunk of 8 elems) -> element row*128 + ((chunk ^ (row&7))*8)
__device__ __forceinline__ int swz_base(int row, int chunk) {
    return row * 128 + ((chunk ^ (row & 7)) << 3);
}

template <bool POOL>
__global__ __launch_bounds__(256, 2)
void k_mlp(const unsigned short* __restrict__ U, int N,
           const unsigned short* __restrict__ WaT, const float* __restrict__ ba,
           const unsigned short* __restrict__ WbT, const float* __restrict__ bb,
           unsigned short* __restrict__ Y,
           const int* __restrict__ batch, float* __restrict__ G) {
    __shared__ unsigned short lA[128 * 128];   // 32 KB: A tile, then T tile, then R tile
    __shared__ unsigned short lW[128 * 128];   // 32 KB: Wa^T, then Wb^T
    __shared__ int bs[128];

    const int tid = threadIdx.x;
    const int lane = tid & 63;
    const int w = tid >> 6;              // wave 0..3
    const int wr = (w >> 1) * 64;        // wave row offset
    const int wc = (w & 1) * 64;         // wave col offset
    const int r0 = blockIdx.x * 128;

    // ---- stage A: bf16 global -> LDS (swizzled), 16B = one 8-elem chunk ----
    {
        const uint4* U4 = (const uint4*)U;
        #pragma unroll
        for (int i = 0; i < 8; ++i) {
            int c = tid + 256 * i;              // 0..2047
            int row = c >> 4, q = c & 15;
            uint4 v = (r0 + row < N) ? U4[(size_t)(r0 + row) * 16 + q]
                                     : make_uint4(0u, 0u, 0u, 0u);
            *(uint4*)&lA[swz_base(row, q)] = v;
        }
    }
    // ---- stage Wa^T ----
    {
        const uint4* Wsrc = (const uint4*)WaT;
        #pragma unroll
        for (int i = 0; i < 8; ++i) {
            int c = tid + 256 * i;
            int row = c >> 4, q = c & 15;
            *(uint4*)&lW[swz_base(row, q)] = Wsrc[c];
        }
    }
    __syncthreads();

    const int am = lane & 15;
    const int kq = (lane >> 4) * 8;             // quad k offset

    f32x4 acc[4][4];
    #pragma unroll
    for (int i = 0; i < 4; ++i)
        #pragma unroll
        for (int j = 0; j < 4; ++j) acc[i][j] = (f32x4){0.f, 0.f, 0.f, 0.f};

    // ---- matmul 1: T = A @ Wa ----
    #pragma unroll
    for (int ks = 0; ks < 4; ++ks) {
        int k0 = ks * 32 + kq;
        bf16x8 af[4], bq[4];
        #pragma unroll
        for (int i = 0; i < 4; ++i)
            af[i] = *(const bf16x8*)&lA[swz_base(wr + i * 16 + am, k0 >> 3)];
        #pragma unroll
        for (int j = 0; j < 4; ++j)
            bq[j] = *(const bf16x8*)&lW[swz_base(wc + j * 16 + am, k0 >> 3)];
        #pragma unroll
        for (int i = 0; i < 4; ++i)
            #pragma unroll
            for (int j = 0; j < 4; ++j)
                acc[i][j] = __builtin_amdgcn_mfma_f32_16x16x32_bf16(af[i], bq[j], acc[i][j], 0, 0, 0);
    }
    __syncthreads();   // all lA/lW reads complete

    // ---- T = relu(acc + ba) -> lA (bf16); restage lW = Wb^T ----
    #pragma unroll
    for (int j = 0; j < 4; ++j) {
        int col = wc + j * 16 + am;
        float bias = ba[col];
        #pragma unroll
        for (int i = 0; i < 4; ++i) {
            int rowb = wr + i * 16 + (lane >> 4) * 4;
            #pragma unroll
            for (int r = 0; r < 4; ++r) {
                float t = acc[i][j][r] + bias;
                t = t > 0.f ? t : 0.f;
                int row = rowb + r;
                lA[swz_base(row, col >> 3) + (col & 7)] = f2bf(t);
            }
        }
    }
    {
        const uint4* Wsrc = (const uint4*)WbT;
        #pragma unroll
        for (int i = 0; i < 8; ++i) {
            int c = tid + 256 * i;
            int row = c >> 4, q = c & 15;
            *(uint4*)&lW[swz_base(row, q)] = Wsrc[c];
        }
    }
    __syncthreads();

    // ---- matmul 2: R = T @ Wb ----
    #pragma unroll
    for (int i = 0; i < 4; ++i)
        #pragma unroll
        for (int j = 0; j < 4; ++j) acc[i][j] = (f32x4){0.f, 0.f, 0.f, 0.f};

    #pragma unroll
    for (int ks = 0; ks < 4; ++ks) {
        int k0 = ks * 32 + kq;
        bf16x8 af[4], bq[4];
        #pragma unroll
        for (int i = 0; i < 4; ++i)
            af[i] = *(const bf16x8*)&lA[swz_base(wr + i * 16 + am, k0 >> 3)];
        #pragma unroll
        for (int j = 0; j < 4; ++j)
            bq[j] = *(const bf16x8*)&lW[swz_base(wc + j * 16 + am, k0 >> 3)];
        #pragma unroll
        for (int i = 0; i < 4; ++i)
            #pragma unroll
            for (int j = 0; j < 4; ++j)
                acc[i][j] = __builtin_amdgcn_mfma_f32_16x16x32_bf16(af[i], bq[j], acc[i][j], 0, 0, 0);
    }

    if (!POOL) {
        // ---- epilogue: Y = relu(acc + bb), bf16 ----
        #pragma unroll
        for (int j = 0; j < 4; ++j) {
            int col = wc + j * 16 + am;
            float bias = bb[col];
            #pragma unroll
            for (int i = 0; i < 4; ++i) {
                int rowb = wr + i * 16 + (lane >> 4) * 4;
                #pragma unroll
                for (int r = 0; r < 4; ++r) {
                    int row = r0 + rowb + r;
                    if (row < N) {
                        float t = acc[i][j][r] + bias;
                        t = t > 0.f ? t : 0.f;
                        Y[(size_t)row * 128 + col] = f2bf(t);
                    }
                }
            }
        }
    } else {
        // ---- epilogue: R = relu(acc+bb) -> LDS (bf16), then segmented pool into G ----
        __syncthreads();   // matmul-2 lA reads complete before overwrite
        #pragma unroll
        for (int j = 0; j < 4; ++j) {
            int col = wc + j * 16 + am;
            float bias = bb[col];
            #pragma unroll
            for (int i = 0; i < 4; ++i) {
                int rowb = wr + i * 16 + (lane >> 4) * 4;
                #pragma unroll
                for (int r = 0; r < 4; ++r) {
                    float t = acc[i][j][r] + bias;
                    t = t > 0.f ? t : 0.f;
                    int row = rowb + r;
                    lA[swz_base(row, col >> 3) + (col & 7)] = f2bf(t);
                }
            }
        }
        if (tid < 128) bs[tid] = (r0 + tid < N) ? batch[r0 + tid] : -1;
        __syncthreads();
        const int col = tid & 127;
        const int half = tid >> 7;
        const int rbeg = half * 64, rend = rbeg + 64;
        float pacc = 0.f;
        int cur = bs[rbeg];
        for (int row = rbeg; row < rend; ++row) {
            int b = bs[row];
            if (b != cur) {
                if (cur >= 0) atomicAdd(&G[(size_t)cur * 128 + col], pacc);
                pacc = 0.f;
                cur = b;
            }
            unsigned short u = lA[swz_base(row, col >> 3) + (col & 7)];
            pacc += __uint_as_float((unsigned)u << 16);
        }
        if (cur >= 0) atomicAdd(&G[(size_t)cur * 128 + col], pacc);
    }
}

// ---------------- head: out = log_softmax(relu(g@Wl1+bl1)@Wl2+bl2) ----------------
__global__ void k_head(const float* __restrict__ G,
                       const float* __restrict__ Wl1, const float* __restrict__ bl1,
                       const float* __restrict__ Wl2, const float* __restrict__ bl2,
                       int C, float* __restrict__ out) {
    __shared__ float sg[128];
    __shared__ float sh[128];
    __shared__ float sl[16];
    int row = blockIdx.x;
    int t = threadIdx.x;
    sg[t] = G[(size_t)row * 128 + t];
    __syncthreads();
    float a = bl1[t];
    for (int k = 0; k < 128; ++k) a += sg[k] * Wl1[k * 128 + t];
    sh[t] = a > 0.f ? a : 0.f;
    __syncthreads();
    if (t < C) {
        float l = bl2[t];
        for (int k = 0; k < 128; ++k) l += sh[k] * Wl2[k * C + t];
        sl[t] = l;
    }
    __syncthreads();
    if (t < C) {
        float m = -1e30f;
        for (int j = 0; j < C; ++j) m = fmaxf(m, sl[j]);
        float s = 0.f;
        for (int j = 0; j < C; ++j) s += __expf(sl[j] - m);
        out[(size_t)row * C + t] = sl[t] - m - __logf(s);
    }
}

extern "C" void kernel_launch(void* const* d_in, const int* in_sizes, int n_in,
                              void* d_out, int out_size, void* d_ws, size_t ws_size,
                              hipStream_t stream) {
    const float* x    = (const float*)d_in[0];
    const int*   ei   = (const int*)d_in[1];     // [2][E]
    const int*   batch= (const int*)d_in[2];
    const float* W1a  = (const float*)d_in[3];
    const float* b1a  = (const float*)d_in[4];
    const float* W1b  = (const float*)d_in[5];
    const float* b1b  = (const float*)d_in[6];
    const float* W2a  = (const float*)d_in[7];
    const float* b2a  = (const float*)d_in[8];
    const float* W2b  = (const float*)d_in[9];
    const float* b2b  = (const float*)d_in[10];
    const float* Wl1  = (const float*)d_in[11];
    const float* bl1  = (const float*)d_in[12];
    const float* Wl2  = (const float*)d_in[13];
    const float* bl2  = (const float*)d_in[14];
    float* out = (float*)d_out;

    const int N = in_sizes[2];
    const int E = in_sizes[1] / 2;
    const int C = in_sizes[13] / 128;

    const int nbuck = (N >> 7) + 1;              // 128 dst per bucket (<=1024 for N<=128k)
    const int epb = (E + NBLK - 1) / NBLK;

    char* p = (char*)d_ws;
    auto alloc = [&](size_t bytes) {
        char* r = p;
        p += (bytes + 255) & ~(size_t)255;
        return r;
    };
    unsigned* xb   = (unsigned*)alloc((size_t)N * 64 * 4);     // x in bf16
    unsigned* hA   = (unsigned*)alloc((size_t)N * 64 * 4);     // agg out (bf16)
    unsigned* hB   = (unsigned*)alloc((size_t)N * 64 * 4);     // conv1 out (bf16)
    float* g       = (float*)alloc((size_t)NUM_GRAPHS * 128 * 4);
    int* rp        = (int*)alloc((size_t)(N + 1) * 4);
    int* srcs      = (int*)alloc((size_t)E * 4);
    unsigned* ebuf = (unsigned*)alloc((size_t)E * 4);
    int* cnt       = (int*)alloc((size_t)nbuck * NBLK * 4);
    int* pref      = (int*)alloc((size_t)nbuck * NBLK * 4);
    int* tot       = (int*)alloc((size_t)1024 * 4);
    unsigned short* wt = (unsigned short*)alloc((size_t)4 * 16384 * 2);
    (void)ws_size; (void)n_in; (void)out_size;

    // CSR build, counting-sort (no global atomics), fused with x->bf16 + zero G
    k_pre<<<NBLK + 2048 + 64, 256, 0, stream>>>(ei + E, E, epb, nbuck, cnt,
                                                x, N * 32, xb, g);
    k_colscan<<<(nbuck + 255) / 256, 256, 0, stream>>>(cnt, nbuck, pref, tot);
    k_scatter<<<NBLK, 256, 0, stream>>>(ei, ei + E, E, epb, pref, tot, nbuck, ebuf);
    k_bucket<<<nbuck + 256, 256, 0, stream>>>(ebuf, tot, nbuck, N, rp, srcs,
                                              W1a, W1b, W2a, W2b, wt);

    const int mb = (N + 127) / 128;
    const int qw = (N + 3) / 4;          // quarter-wave agg: 4 nodes per wave
    const int qb = (qw + 3) / 4;         // 4 waves per block

    // conv1
    k_aggq<<<qb, 256, 0, stream>>>((const uint4*)xb, rp, srcs, N, (uint4*)hA);
    k_mlp<false><<<mb, 256, 0, stream>>>((const unsigned short*)hA, N, wt, b1a,
                                         wt + 16384, b1b, (unsigned short*)hB,
                                         nullptr, nullptr);
    // conv2 (+ fused global_add_pool into G)
    k_aggq<<<qb, 256, 0, stream>>>((const uint4*)hB, rp, srcs, N, (uint4*)hA);
    k_mlp<true><<<mb, 256, 0, stream>>>((const unsigned short*)hA, N, wt + 2 * 16384, b2a,
                                        wt + 3 * 16384, b2b, nullptr,
                                        batch, g);
    // head
    k_head<<<NUM_GRAPHS, 128, 0, stream>>>(g, Wl1, bl1, Wl2, bl2, C, out);
}